// Round 1
// baseline (6081.026 us; speedup 1.0000x reference)
//
#include <hip/hip_runtime.h>
#include <hip/hip_bf16.h>

typedef __bf16 bf16_t;
typedef __bf16 bf16x8 __attribute__((ext_vector_type(8)));
typedef float f32x4 __attribute__((ext_vector_type(4)));

#define B_   32
#define S_   512
#define E_   512
#define H_   1024
#define G3   3072
#define MTOT 16384  // B*S

// ---------------- f32 -> bf16 conversion ----------------
__global__ __launch_bounds__(256) void cvt_f32_bf16(const float* __restrict__ src,
                                                    bf16_t* __restrict__ dst, int n) {
    int i = (blockIdx.x * 256 + threadIdx.x) * 8;
    if (i + 8 <= n) {
        float4 a = *(const float4*)(src + i);
        float4 b = *(const float4*)(src + i + 4);
        bf16x8 v;
        v[0] = (bf16_t)a.x; v[1] = (bf16_t)a.y; v[2] = (bf16_t)a.z; v[3] = (bf16_t)a.w;
        v[4] = (bf16_t)b.x; v[5] = (bf16_t)b.y; v[6] = (bf16_t)b.z; v[7] = (bf16_t)b.w;
        *(bf16x8*)(dst + i) = v;
    } else {
        for (; i < n; ++i) dst[i] = (bf16_t)src[i];
    }
}

__global__ __launch_bounds__(256) void zero_bf16(bf16_t* __restrict__ p, int n) {
    int i = (blockIdx.x * 256 + threadIdx.x) * 8;
    if (i + 8 <= n) {
        bf16x8 z;
        for (int j = 0; j < 8; ++j) z[j] = (bf16_t)0.f;
        *(bf16x8*)(p + i) = z;
    }
}

// ---------------- phase 1: xg = gather(emb,x) @ W_ih^T + b_ih ----------------
// M=16384, N=3072, K=512. Tile 128x128, BK=32, 4 waves (2x2 of 64x64).
__global__ __launch_bounds__(256) void xg_gemm(const int* __restrict__ x,
                                               const float* __restrict__ emb,
                                               const bf16_t* __restrict__ Wihb,
                                               const float* __restrict__ b_ih,
                                               bf16_t* __restrict__ xgb) {
    __shared__ __attribute__((aligned(16))) bf16_t As[128][40];  // pad stride 40 (80B)
    __shared__ __attribute__((aligned(16))) bf16_t Bs[128][40];

    const int tid  = threadIdx.x;
    const int lane = tid & 63, wave = tid >> 6;
    const int wm = wave >> 1, wn = wave & 1;
    const int c16 = lane & 15, r16 = lane >> 4;
    const int tileN = blockIdx.x, tileM = blockIdx.y;
    const int sr = tid >> 1;          // staging row 0..127
    const int sh = (tid & 1) * 16;    // staging col offset (16 elems)

    const int tok = x[tileM * 128 + sr];
    const float*  asrc = emb  + (size_t)tok * E_;
    const bf16_t* bsrc = Wihb + (size_t)(tileN * 128 + sr) * E_;

    f32x4 zero = {0.f, 0.f, 0.f, 0.f};
    f32x4 acc[4][4];
    for (int i = 0; i < 4; ++i)
        for (int j = 0; j < 4; ++j) acc[i][j] = zero;

    for (int kt = 0; kt < 16; ++kt) {
        const int k0 = kt * 32;
        // stage A: load f32, convert to bf16
        float4 a0 = *(const float4*)(asrc + k0 + sh);
        float4 a1 = *(const float4*)(asrc + k0 + sh + 4);
        float4 a2 = *(const float4*)(asrc + k0 + sh + 8);
        float4 a3 = *(const float4*)(asrc + k0 + sh + 12);
        bf16x8 av0, av1;
        av0[0]=(bf16_t)a0.x; av0[1]=(bf16_t)a0.y; av0[2]=(bf16_t)a0.z; av0[3]=(bf16_t)a0.w;
        av0[4]=(bf16_t)a1.x; av0[5]=(bf16_t)a1.y; av0[6]=(bf16_t)a1.z; av0[7]=(bf16_t)a1.w;
        av1[0]=(bf16_t)a2.x; av1[1]=(bf16_t)a2.y; av1[2]=(bf16_t)a2.z; av1[3]=(bf16_t)a2.w;
        av1[4]=(bf16_t)a3.x; av1[5]=(bf16_t)a3.y; av1[6]=(bf16_t)a3.z; av1[7]=(bf16_t)a3.w;
        *(bf16x8*)&As[sr][sh]     = av0;
        *(bf16x8*)&As[sr][sh + 8] = av1;
        // stage B: already bf16
        bf16x8 bv0 = *(const bf16x8*)(bsrc + k0 + sh);
        bf16x8 bv1 = *(const bf16x8*)(bsrc + k0 + sh + 8);
        *(bf16x8*)&Bs[sr][sh]     = bv0;
        *(bf16x8*)&Bs[sr][sh + 8] = bv1;
        __syncthreads();

        bf16x8 af[4], bfv[4];
#pragma unroll
        for (int mi = 0; mi < 4; ++mi)
            af[mi] = *(const bf16x8*)&As[wm * 64 + mi * 16 + c16][r16 * 8];
#pragma unroll
        for (int ni = 0; ni < 4; ++ni)
            bfv[ni] = *(const bf16x8*)&Bs[wn * 64 + ni * 16 + c16][r16 * 8];
#pragma unroll
        for (int mi = 0; mi < 4; ++mi)
#pragma unroll
            for (int ni = 0; ni < 4; ++ni)
                acc[mi][ni] = __builtin_amdgcn_mfma_f32_16x16x32_bf16(af[mi], bfv[ni], acc[mi][ni], 0, 0, 0);
        __syncthreads();
    }

    // epilogue: add b_ih, store bf16 to xgb[R][col]
#pragma unroll
    for (int ni = 0; ni < 4; ++ni) {
        const int col = tileN * 128 + wn * 64 + ni * 16 + c16;
        const float bi = b_ih[col];
#pragma unroll
        for (int mi = 0; mi < 4; ++mi) {
            const int R0 = tileM * 128 + wm * 64 + mi * 16 + r16 * 4;
#pragma unroll
            for (int r = 0; r < 4; ++r)
                xgb[(size_t)(R0 + r) * G3 + col] = (bf16_t)(acc[mi][ni][r] + bi);
        }
    }
}

// ---------------- phase 2: one GRU step ----------------
// Grid = 32 WGs; WG owns 32 H-columns, computes all 3 gates (M=32,N=96,K=1024).
// 4 waves split K (256 each); LDS reduce; then elementwise gates.
__global__ __launch_bounds__(256) void gru_step(int s,
                                                const bf16_t* __restrict__ xgb,
                                                const bf16_t* __restrict__ Whh,
                                                const float* __restrict__ b_hh,
                                                const bf16_t* __restrict__ h_rd,
                                                bf16_t* __restrict__ h_wr,
                                                float* __restrict__ out,
                                                float* __restrict__ state) {
    __shared__ float red[4][32][96];  // 48 KB
    const int tid = threadIdx.x, lane = tid & 63, wave = tid >> 6;
    const int c16 = lane & 15, r16 = lane >> 4;
    const int j0 = blockIdx.x * 32;
    const int kb = wave * 256;

    f32x4 zero = {0.f, 0.f, 0.f, 0.f};
    f32x4 acc[3][2][2];
    for (int g = 0; g < 3; ++g)
        for (int a = 0; a < 2; ++a)
            for (int b = 0; b < 2; ++b) acc[g][a][b] = zero;

#pragma unroll
    for (int kk = 0; kk < 8; ++kk) {
        const int k = kb + kk * 32 + r16 * 8;
        bf16x8 a0 = *(const bf16x8*)(h_rd + (size_t)c16 * H_ + k);
        bf16x8 a1 = *(const bf16x8*)(h_rd + (size_t)(16 + c16) * H_ + k);
#pragma unroll
        for (int g = 0; g < 3; ++g) {
#pragma unroll
            for (int nb = 0; nb < 2; ++nb) {
                const bf16_t* wrow = Whh + (size_t)(g * H_ + j0 + nb * 16 + c16) * H_;
                bf16x8 bv = *(const bf16x8*)(wrow + k);
                acc[g][0][nb] = __builtin_amdgcn_mfma_f32_16x16x32_bf16(a0, bv, acc[g][0][nb], 0, 0, 0);
                acc[g][1][nb] = __builtin_amdgcn_mfma_f32_16x16x32_bf16(a1, bv, acc[g][1][nb], 0, 0, 0);
            }
        }
    }

    // write per-wave partials: b = mb*16 + r16*4 + r, col = g*32 + nb*16 + c16
#pragma unroll
    for (int g = 0; g < 3; ++g)
#pragma unroll
        for (int mb = 0; mb < 2; ++mb)
#pragma unroll
            for (int nb = 0; nb < 2; ++nb)
#pragma unroll
                for (int r = 0; r < 4; ++r)
                    red[wave][mb * 16 + r16 * 4 + r][g * 32 + nb * 16 + c16] = acc[g][mb][nb][r];
    __syncthreads();

    // reduce K-partials + gates: 1024 (b, jl) pairs
    for (int idx = tid; idx < 1024; idx += 256) {
        const int b = idx >> 5, jl = idx & 31;
        const int j = j0 + jl;
        float hr = 0.f, hz = 0.f, hn = 0.f;
#pragma unroll
        for (int w = 0; w < 4; ++w) {
            hr += red[w][b][jl];
            hz += red[w][b][32 + jl];
            hn += red[w][b][64 + jl];
        }
        hr += b_hh[j]; hz += b_hh[H_ + j]; hn += b_hh[2 * H_ + j];
        const size_t xbase = (size_t)(b * S_ + s) * G3;
        const float xr = (float)xgb[xbase + j];
        const float xz = (float)xgb[xbase + H_ + j];
        const float xn = (float)xgb[xbase + 2 * H_ + j];
        const float hold = (s > 0) ? out[((size_t)b * S_ + (s - 1)) * H_ + j] : 0.f;
        const float rg = 1.f / (1.f + __expf(-(xr + hr)));
        const float zg = 1.f / (1.f + __expf(-(xz + hz)));
        const float ng = tanhf(xn + rg * hn);
        const float hnew = (1.f - zg) * ng + zg * hold;
        out[((size_t)b * S_ + s) * H_ + j] = hnew;
        h_wr[b * H_ + j] = (bf16_t)hnew;
        if (s == S_ - 1) state[b * H_ + j] = hnew;
    }
}

// ---------------- phase 3: LayerNorm in place (wave per row) ----------------
__global__ __launch_bounds__(256) void ln_kernel(float* __restrict__ out,
                                                 const float* __restrict__ gamma,
                                                 const float* __restrict__ beta) {
    const int wave = threadIdx.x >> 6, lane = threadIdx.x & 63;
    const size_t row = (size_t)blockIdx.x * 4 + wave;
    float* p = out + row * H_;
    float4 v[4];
    float sum = 0.f, sq = 0.f;
#pragma unroll
    for (int i = 0; i < 4; ++i) {
        v[i] = *(const float4*)(p + i * 256 + lane * 4);
        sum += v[i].x + v[i].y + v[i].z + v[i].w;
        sq  += v[i].x * v[i].x + v[i].y * v[i].y + v[i].z * v[i].z + v[i].w * v[i].w;
    }
#pragma unroll
    for (int o = 32; o > 0; o >>= 1) {
        sum += __shfl_xor(sum, o);
        sq  += __shfl_xor(sq, o);
    }
    const float mean = sum * (1.f / 1024.f);
    const float var  = sq * (1.f / 1024.f) - mean * mean;
    const float inv  = rsqrtf(var + 1e-5f);
#pragma unroll
    for (int i = 0; i < 4; ++i) {
        const int c = i * 256 + lane * 4;
        float4 g4 = *(const float4*)(gamma + c);
        float4 b4 = *(const float4*)(beta + c);
        float4 y;
        y.x = (v[i].x - mean) * inv * g4.x + b4.x;
        y.y = (v[i].y - mean) * inv * g4.y + b4.y;
        y.z = (v[i].z - mean) * inv * g4.z + b4.z;
        y.w = (v[i].w - mean) * inv * g4.w + b4.w;
        *(float4*)(p + c) = y;
    }
}

// ---------------- launch ----------------
extern "C" void kernel_launch(void* const* d_in, const int* in_sizes, int n_in,
                              void* d_out, int out_size, void* d_ws, size_t ws_size,
                              hipStream_t stream) {
    const int*   x     = (const int*)d_in[0];
    const float* emb   = (const float*)d_in[1];
    const float* W_ih  = (const float*)d_in[2];
    const float* W_hh  = (const float*)d_in[3];
    const float* b_ih  = (const float*)d_in[4];
    const float* b_hh  = (const float*)d_in[5];
    const float* gamma = (const float*)d_in[6];
    const float* beta  = (const float*)d_in[7];
    float* out   = (float*)d_out;
    float* state = out + (size_t)MTOT * H_;

    char* ws = (char*)d_ws;
    bf16_t* Wihb = (bf16_t*)(ws);                      // 3,145,728 B
    bf16_t* Whhb = (bf16_t*)(ws + 3145728);            // 6,291,456 B
    bf16_t* xgb  = (bf16_t*)(ws + 9437184);            // 100,663,296 B
    bf16_t* hbuf = (bf16_t*)(ws + 110100480);          // 2 x 32768 bf16

    cvt_f32_bf16<<<768,  256, 0, stream>>>(W_ih, Wihb, 1572864);
    cvt_f32_bf16<<<1536, 256, 0, stream>>>(W_hh, Whhb, 3145728);
    zero_bf16<<<16, 256, 0, stream>>>(hbuf, 32768);

    dim3 gg(24, 128);
    xg_gemm<<<gg, 256, 0, stream>>>(x, emb, Wihb, b_ih, xgb);

    for (int s = 0; s < S_; ++s) {
        bf16_t* hr = hbuf + (size_t)(s & 1) * 32768;
        bf16_t* hw = hbuf + (size_t)((s + 1) & 1) * 32768;
        gru_step<<<32, 256, 0, stream>>>(s, xgb, Whhb, b_hh, hr, hw, out, state);
    }

    ln_kernel<<<4096, 256, 0, stream>>>(out, gamma, beta);
}